// Round 12
// baseline (78.236 us; speedup 1.0000x reference)
//
#include <hip/hip_runtime.h>

// IDW, POWER=2.0 -> w = 1/d2 (sqrt cancels). out = sum(w*v)/sum(w).
// B=2, P=131072, S=512.
// R17: RESTORE R15 (best passing, 77.9us). R16 (expansion-form d2) FAILED
//   absmax 0.17: cancellation error in (qg+qs)-2s.g is relative to O(1)
//   input magnitudes (~1e-7 residue), so near-station points (true d2~1e-7)
//   get O(1)-wrong weights that dominate the weighted mean. The subtraction
//   form's 4 ops/station-pair is REQUIRED for correctness -> instruction-mix
//   levers are exhausted (R9: trans mix calibrated; R15: 16-way combine
//   optimal; R16: op-cut breaks numerics).
//   Ledger: 40us fill (harness) + 12.4us graph overhead + ~25.5us kernel
//   (57% duty over a proven-minimal 14.6us issue floor; duty >60% at full
//   chip never achieved across 10 structural variants: {LDS,SMEM} x
//   {1,2,4 w/SIMD} x {GPT 1-8} x {rot,direct,dbuf} x station-split).
//   This is the structural floor; expect <<ROOFLINE>> next round.
// Structure (R15): GPT=4, 256 blocks (1 blk/CU, 1 wave/SIMD), LDS packed
//   {x,y,v}, 16-way hierarchical rcp-combine (133 plain + 1 trans per 16
//   stations/point), double-buffered 16-station groups, hand-unrolled x2
//   (rotation = register renaming). EPS2 folded in each d2 fma chain
//   (exact at d2==0, like ref). __launch_bounds__(256,1).

#define BLOCK 256
#define S_MAX 512
#define GPT 4

__global__ __launch_bounds__(BLOCK, 1) void idw_kernel(
    const float* __restrict__ station_coords,  // (B, S, 2)
    const float* __restrict__ station_values,  // (B, S)
    const float* __restrict__ grid_points,     // (B, P, 2)
    float* __restrict__ out,                   // (B, P)
    int P, int S) {

    __shared__ float st[S_MAX * 3];  // packed {x,y,v}, 12B/station

    const int b = blockIdx.y;
    const float2* __restrict__ sc2 = (const float2*)(station_coords) + (size_t)b * S;
    const float*  __restrict__ svb = station_values + (size_t)b * S;

    for (int i = threadIdx.x; i < S; i += BLOCK) {
        const float2 c = sc2[i];
        st[3 * i + 0] = c.x;
        st[3 * i + 1] = c.y;
        st[3 * i + 2] = svb[i];
    }
    __syncthreads();

    const int tid = blockIdx.x * BLOCK + threadIdx.x;
    const float4* __restrict__ gp4 = (const float4*)grid_points + (size_t)b * (P / 2);
    const float4 ga = gp4[2 * tid + 0];
    const float4 gb = gp4[2 * tid + 1];
    const float gx0 = ga.x, gy0 = ga.y, gx1 = ga.z, gy1 = ga.w;
    const float gx2 = gb.x, gy2 = gb.y, gx3 = gb.z, gy3 = gb.w;

    constexpr float EPS  = 1.1920928955078125e-07f;
    constexpr float EPS2 = EPS * EPS;

    float ws0 = 0.0f, vs0 = 0.0f, ws1 = 0.0f, vs1 = 0.0f;
    float ws2 = 0.0f, vs2 = 0.0f, ws3 = 0.0f, vs3 = 0.0f;

    const float4* __restrict__ st4 = (const float4*)st;

    // 4 stations A..D (f0,f1,f2; layout f0=Ax Ay Av Bx | f1=By Bv Cx Cy |
    // f2=Cv Dx Dy Dv) vs one point -> partial numerators + product, NO rcp.
    // 29 plain ops.
    auto half4 = [&](float gx, float gy,
                     const float4& f0, const float4& f1, const float4& f2,
                     float& Pq, float& Wq, float& Vq) {
        const float dxa = gx - f0.x, dya = gy - f0.y;
        const float a = fmaf(dxa, dxa, fmaf(dya, dya, EPS2));
        const float dxb = gx - f0.w, dyb = gy - f1.x;
        const float bq = fmaf(dxb, dxb, fmaf(dyb, dyb, EPS2));
        const float dxc = gx - f1.z, dyc = gy - f1.w;
        const float c = fmaf(dxc, dxc, fmaf(dyc, dyc, EPS2));
        const float dxd = gx - f2.y, dyd = gy - f2.z;
        const float d = fmaf(dxd, dxd, fmaf(dyd, dyd, EPS2));
        const float pab = a * bq, pcd = c * d;
        const float sab = a + bq, scd = c + d;
        const float nab = fmaf(f1.y, a, f0.z * bq);  // vB*a + vA*b
        const float ncd = fmaf(f2.w, c, f2.x * d);   // vD*c + vC*d
        Wq = fmaf(sab, pcd, scd * pab);
        Vq = fmaf(nab, pcd, ncd * pab);
        Pq = pab * pcd;
    };

    // 16 stations (12 float4) vs one point: 4 half4 + 3 merges + 1 rcp.
    // 133 plain + 1 trans.
    auto pair16 = [&](float gx, float gy, float& ws, float& vs,
                      const float4 (&f)[12]) {
        float P1, W1, V1, P2, W2, V2, P3, W3, V3, P4, W4, V4;
        half4(gx, gy, f[0], f[1], f[2], P1, W1, V1);
        half4(gx, gy, f[3], f[4], f[5], P2, W2, V2);
        half4(gx, gy, f[6], f[7], f[8], P3, W3, V3);
        half4(gx, gy, f[9], f[10], f[11], P4, W4, V4);
        // 8-way merges
        const float P12 = P1 * P2;
        const float W12 = fmaf(W1, P2, W2 * P1);
        const float V12 = fmaf(V1, P2, V2 * P1);
        const float P34 = P3 * P4;
        const float W34 = fmaf(W3, P4, W4 * P3);
        const float V34 = fmaf(V3, P4, V4 * P3);
        // 16-way merge + single rcp
        const float P16 = P12 * P34;
        const float W16 = fmaf(W12, P34, W34 * P12);
        const float V16 = fmaf(V12, P34, V34 * P12);
        const float r = __builtin_amdgcn_rcpf(P16);
        ws = fmaf(W16, r, ws);
        vs = fmaf(V16, r, vs);
    };

    auto do4pts = [&](const float4 (&f)[12]) {
        pair16(gx0, gy0, ws0, vs0, f);
        pair16(gx1, gy1, ws1, vs1, f);
        pair16(gx2, gy2, ws2, vs2, f);
        pair16(gx3, gy3, ws3, vs3, f);
    };

    // 32 pairs of 16 stations; double-buffered, hand-unrolled x2 so the
    // rotation is pure register renaming (no v_mov).
    float4 cb[12], nb[12];
#pragma unroll
    for (int i = 0; i < 12; ++i) cb[i] = st4[i];

    for (int j = 0; j < 15; ++j) {
#pragma unroll
        for (int i = 0; i < 12; ++i) nb[i] = st4[12 * (2 * j + 1) + i];
        do4pts(cb);   // pair 2j
#pragma unroll
        for (int i = 0; i < 12; ++i) cb[i] = st4[12 * (2 * j + 2) + i];
        do4pts(nb);   // pair 2j+1
    }
    // cb = pair 30; load pair 31 and finish.
#pragma unroll
    for (int i = 0; i < 12; ++i) nb[i] = st4[12 * 31 + i];
    do4pts(cb);
    do4pts(nb);

    const float4 res = make_float4(vs0 / ws0, vs1 / ws1, vs2 / ws2, vs3 / ws3);
    ((float4*)out)[(size_t)b * (P / 4) + tid] = res;
}

extern "C" void kernel_launch(void* const* d_in, const int* in_sizes, int n_in,
                              void* d_out, int out_size, void* d_ws, size_t ws_size,
                              hipStream_t stream) {
    const float* station_coords = (const float*)d_in[0];
    const float* station_values = (const float*)d_in[1];
    const float* grid_points    = (const float*)d_in[2];
    float* out = (float*)d_out;

    const int B = 2;
    const int S = in_sizes[1] / B;   // 512
    const int P = out_size / B;      // 131072

    dim3 grid(P / (BLOCK * GPT), B);  // 128 x 2 = 256 blocks, 1 per CU
    dim3 block(BLOCK);
    idw_kernel<<<grid, block, 0, stream>>>(station_coords, station_values,
                                           grid_points, out, P, S);
}